// Round 4
// baseline (1413.645 us; speedup 1.0000x reference)
//
#include <hip/hip_runtime.h>
#include <hip/hip_bf16.h>

#define DIM 128
#define BNODES 256      // dst nodes per bucket (dst>>8 = bucket, dst&255 = local)
#define NBMAX 512       // scan capacity (nb = 391 for N=100000)

typedef __attribute__((ext_vector_type(8))) short bf16x8;
typedef __attribute__((ext_vector_type(4))) float f32x4;

__device__ inline ushort f2bf(float f) {
    uint u = __float_as_uint(f);
    u += 0x7fffu + ((u >> 16) & 1u);   // RNE
    return (ushort)(u >> 16);
}
__device__ inline uint pack2(float lo, float hi) {
    return (uint)f2bf(lo) | ((uint)f2bf(hi) << 16);
}

// out[n][j] = relu(b[j] + sum_k in[n][k] * W[j][k])  (+ xres[n][j] if RESID)
// MFMA 16x16x32 bf16; one wave per 16-row tile (in-place safe for RESID).
// A and B use the same assumed k-bijection (dot invariant); C layout is the
// m89-verified col=lane&15, row=(lane>>4)*4+reg.
template<bool RESID, bool BF16OUT>
__global__ __launch_bounds__(256, 2)
void linear_mfma_kernel(const float* in, const float* __restrict__ W,
                        const float* __restrict__ b, const float* __restrict__ xres,
                        void* outv, int n_tiles)
{
    __shared__ uint4 Wl[128 * 16];   // 32 KB, 16B-chunk XOR swizzle

    const int t = threadIdx.x;
    for (int q = t; q < 2048; q += 256) {
        const int j = q >> 4, c = q & 15;
        const float4 lo = ((const float4*)(W + j * 128 + c * 8))[0];
        const float4 hi = ((const float4*)(W + j * 128 + c * 8))[1];
        uint4 pk;
        pk.x = pack2(lo.x, lo.y); pk.y = pack2(lo.z, lo.w);
        pk.z = pack2(hi.x, hi.y); pk.w = pack2(hi.z, hi.w);
        Wl[j * 16 + (c ^ (j & 15))] = pk;
    }
    __syncthreads();

    const int lane = t & 63;
    const int lo4 = lane & 15;
    const int g   = lane >> 4;

    float bias[8];
    #pragma unroll
    for (int ct = 0; ct < 8; ++ct) bias[ct] = b[ct * 16 + lo4];

    const int wid = (blockIdx.x * 256 + t) >> 6;
    const int nw  = (gridDim.x * 256) >> 6;

    for (int tile = wid; tile < n_tiles; tile += nw) {
        const int arow = tile * 16 + lo4;
        const float4* ap = (const float4*)(in + (size_t)arow * DIM + g * 32);
        float4 v[8];
        #pragma unroll
        for (int i = 0; i < 8; ++i) v[i] = ap[i];

        bf16x8 afrag[4];
        #pragma unroll
        for (int ks = 0; ks < 4; ++ks) {
            union { bf16x8 v8; uint u[4]; } a;
            a.u[0] = pack2(v[2*ks].x,   v[2*ks].y);
            a.u[1] = pack2(v[2*ks].z,   v[2*ks].w);
            a.u[2] = pack2(v[2*ks+1].x, v[2*ks+1].y);
            a.u[3] = pack2(v[2*ks+1].z, v[2*ks+1].w);
            afrag[ks] = a.v8;
        }

        f32x4 acc[8];
        #pragma unroll
        for (int ct = 0; ct < 8; ++ct)
            acc[ct] = (f32x4){bias[ct], bias[ct], bias[ct], bias[ct]};

        #pragma unroll
        for (int ks = 0; ks < 4; ++ks) {
            #pragma unroll
            for (int ct = 0; ct < 8; ++ct) {
                const int jrow = ct * 16 + lo4;
                const bf16x8 bfrag = *((const bf16x8*)&Wl[jrow * 16 + ((g * 4 + ks) ^ lo4)]);
                acc[ct] = __builtin_amdgcn_mfma_f32_16x16x32_bf16(afrag[ks], bfrag, acc[ct], 0, 0, 0);
            }
        }

        #pragma unroll
        for (int ct = 0; ct < 8; ++ct) {
            #pragma unroll
            for (int r = 0; r < 4; ++r) {
                const int orow = tile * 16 + g * 4 + r;
                const int ocol = ct * 16 + lo4;
                float val = fmaxf(acc[ct][r], 0.f);
                if constexpr (RESID) val += xres[(size_t)orow * DIM + ocol];
                if constexpr (BF16OUT)
                    ((ushort*)outv)[(size_t)orow * DIM + ocol] = f2bf(val);
                else
                    ((float*)outv)[(size_t)orow * DIM + ocol] = val;
            }
        }
    }
}

// Pass 1: global per-bucket histogram (block-local LDS hist, then one atomic per bucket)
__global__ __launch_bounds__(256)
void bucket_count_kernel(const int* __restrict__ ei, int* __restrict__ ghist,
                         int n_edges, int nb)
{
    __shared__ int h[NBMAX];
    const int t = threadIdx.x;
    for (int i = t; i < nb; i += 256) h[i] = 0;
    __syncthreads();
    const int stride = gridDim.x * 256;
    for (int e = blockIdx.x * 256 + t; e < n_edges; e += stride)
        atomicAdd(&h[ei[n_edges + e] >> 8], 1);
    __syncthreads();
    for (int i = t; i < nb; i += 256)
        if (h[i]) atomicAdd(&ghist[i], h[i]);
}

// Pass 2: exclusive scan of nb (<512) bucket counts -> goff, gcur
__global__ __launch_bounds__(512)
void bucket_scan_kernel(const int* __restrict__ ghist, int* __restrict__ goff,
                        int* __restrict__ gcur, int nb, int total)
{
    __shared__ int s[512];
    const int t = threadIdx.x;
    const int v = t < nb ? ghist[t] : 0;
    s[t] = v;
    __syncthreads();
    for (int off = 1; off < 512; off <<= 1) {
        const int add = t >= off ? s[t - off] : 0;
        __syncthreads();
        s[t] += add;
        __syncthreads();
    }
    const int excl = s[t] - v;
    if (t < nb) { goff[t] = excl; gcur[t] = excl; }
    if (t == 0) goff[nb] = total;
}

// Pass 3: scatter packed edges (src<<8 | dst_local) into bucket regions.
// Per-block LDS hist -> one global atomicAdd per (block,bucket) reserves a
// contiguous range -> writes land in ~64B runs (L2-absorbed).
__global__ __launch_bounds__(256)
void bucket_scatter_kernel(const int* __restrict__ ei, int* __restrict__ gcur,
                           uint* __restrict__ bedges, int n_edges, int nb)
{
    __shared__ int histL[NBMAX];
    __shared__ int curL[NBMAX];
    const int t = threadIdx.x;
    for (int i = t; i < nb; i += 256) histL[i] = 0;
    __syncthreads();
    const int chunk = (n_edges + gridDim.x - 1) / gridDim.x;
    const int e0 = blockIdx.x * chunk;
    const int e1 = min(e0 + chunk, n_edges);
    for (int e = e0 + t; e < e1; e += 256)
        atomicAdd(&histL[ei[n_edges + e] >> 8], 1);
    __syncthreads();
    for (int i = t; i < nb; i += 256)
        curL[i] = histL[i] ? atomicAdd(&gcur[i], histL[i]) : 0;
    __syncthreads();
    for (int e = e0 + t; e < e1; e += 256) {
        const int src = ei[e];
        const int dst = ei[n_edges + e];
        const int b = dst >> 8;
        const int pos = atomicAdd(&curL[b], 1);
        bedges[pos] = ((uint)src << 8) | (uint)(dst & 255);
    }
}

// Pass 4 (fused gather): one block per (bucket, col-half). 256x64 fp32 tile in
// 64KB LDS; each 32-lane group handles 4 edges/iter: broadcast packed word,
// coalesced 128B msg half-row read, ds_add_f32 accumulation. Tail edges are
// clamped + weighted by 0 (branchless). Full coverage -> no agg memset needed.
__global__ __launch_bounds__(256)
void fused_gather_kernel(const uint* __restrict__ msg, const int* __restrict__ goff,
                         const uint* __restrict__ bedges, float* __restrict__ agg,
                         int n_nodes)
{
    __shared__ float aggL[BNODES * 64];   // 64 KB

    const int t = threadIdx.x;
    const int b = blockIdx.x >> 1;
    const int h = blockIdx.x & 1;

    float4* az = (float4*)aggL;
    for (int i = t; i < BNODES * 16; i += 256) az[i] = make_float4(0.f, 0.f, 0.f, 0.f);
    __syncthreads();

    const int s0 = goff[b], s1 = goff[b + 1];
    const int g = t >> 5, l = t & 31;
    const int colu = h * 32 + l;          // uint col index within msg row

    for (int base = s0 + g * 4; base < s1; base += 32) {
        const int i1 = min(base + 1, s1 - 1);
        const int i2 = min(base + 2, s1 - 1);
        const int i3 = min(base + 3, s1 - 1);
        const float w1 = base + 1 < s1 ? 1.f : 0.f;
        const float w2 = base + 2 < s1 ? 1.f : 0.f;
        const float w3 = base + 3 < s1 ? 1.f : 0.f;
        const uint p0 = bedges[base];
        const uint p1 = bedges[i1];
        const uint p2 = bedges[i2];
        const uint p3 = bedges[i3];
        const uint m0 = msg[(size_t)(p0 >> 8) * 64 + colu];
        const uint m1 = msg[(size_t)(p1 >> 8) * 64 + colu];
        const uint m2 = msg[(size_t)(p2 >> 8) * 64 + colu];
        const uint m3 = msg[(size_t)(p3 >> 8) * 64 + colu];
        const int d0 = (int)(p0 & 255u) * 64 + 2 * l;
        const int d1 = (int)(p1 & 255u) * 64 + 2 * l;
        const int d2 = (int)(p2 & 255u) * 64 + 2 * l;
        const int d3 = (int)(p3 & 255u) * 64 + 2 * l;
        atomicAdd(&aggL[d0],     __uint_as_float(m0 << 16));
        atomicAdd(&aggL[d0 + 1], __uint_as_float(m0 & 0xffff0000u));
        atomicAdd(&aggL[d1],     w1 * __uint_as_float(m1 << 16));
        atomicAdd(&aggL[d1 + 1], w1 * __uint_as_float(m1 & 0xffff0000u));
        atomicAdd(&aggL[d2],     w2 * __uint_as_float(m2 << 16));
        atomicAdd(&aggL[d2 + 1], w2 * __uint_as_float(m2 & 0xffff0000u));
        atomicAdd(&aggL[d3],     w3 * __uint_as_float(m3 << 16));
        atomicAdd(&aggL[d3 + 1], w3 * __uint_as_float(m3 & 0xffff0000u));
    }
    __syncthreads();

    const int node0 = b * BNODES;
    for (int i = t; i < BNODES * 16; i += 256) {
        const int dl = i >> 4, c4 = i & 15;
        const int node = node0 + dl;
        if (node < n_nodes)
            ((float4*)(agg + (size_t)node * DIM + h * 64))[c4] = ((float4*)&aggL[dl * 64])[c4];
    }
}

extern "C" void kernel_launch(void* const* d_in, const int* in_sizes, int n_in,
                              void* d_out, int out_size, void* d_ws, size_t ws_size,
                              hipStream_t stream)
{
    const float* x  = (const float*)d_in[0];
    const int*   ei = (const int*)d_in[1];
    const float* Wm = (const float*)d_in[2];
    const float* bm = (const float*)d_in[3];
    const float* Wu = (const float*)d_in[4];
    const float* bu = (const float*)d_in[5];

    const int N = in_sizes[0] / DIM;   // 100000
    const int E = in_sizes[1] / 2;     // 1600000
    const int nb = (N + BNODES - 1) / BNODES;   // 391

    // workspace: msg 25.6MB | hist/offs/cursors ~5KB | bedges 6.4MB  (~32MB < 51.2MB proven)
    char* ws = (char*)d_ws;
    ushort* msg = (ushort*)ws;
    size_t o = (size_t)N * DIM * sizeof(ushort);
    int* ghist = (int*)(ws + o); o += (size_t)NBMAX * 4;
    int* goff  = (int*)(ws + o); o += (size_t)(NBMAX + 1) * 4;
    int* gcur  = (int*)(ws + o); o += (size_t)NBMAX * 4;
    o = (o + 255) & ~(size_t)255;
    uint* bedges = (uint*)(ws + o);

    float* out = (float*)d_out;
    float* agg = out;                  // agg lives in d_out; update runs in-place

    const int n_tiles = N / 16;

    // 1) messages (bf16) = relu(x @ Wm^T + bm) -> ws
    linear_mfma_kernel<false, true><<<512, 256, 0, stream>>>(x, Wm, bm, nullptr, msg, n_tiles);

    // 2) bucket CSR (coarse, 256 nodes/bucket)
    hipMemsetAsync(ghist, 0, (size_t)nb * 4, stream);
    bucket_count_kernel<<<256, 256, 0, stream>>>(ei, ghist, E, nb);
    bucket_scan_kernel<<<1, 512, 0, stream>>>(ghist, goff, gcur, nb, E);
    bucket_scatter_kernel<<<256, 256, 0, stream>>>(ei, gcur, bedges, E, nb);

    // 3) fused gather: LDS fp32 tiles, ds_add_f32, coalesced writeout -> d_out
    fused_gather_kernel<<<nb * 2, 256, 0, stream>>>((const uint*)msg, goff, bedges, agg, N);

    // 4) out = relu(agg @ Wu^T + bu) + x   (in-place on d_out)
    linear_mfma_kernel<true, false><<<512, 256, 0, stream>>>(agg, Wu, bu, x, out, n_tiles);
}

// Round 5
// 169.928 us; speedup vs baseline: 8.3191x; 8.3191x over previous
//
#include <hip/hip_runtime.h>
#include <hip/hip_bf16.h>

#define DIM 128
#define BNODES 128      // dst nodes per bucket (dst>>7 = bucket, dst&127 = local)
#define NBMAX 1024      // bucket-count capacity (nb = 782 for N=100000)
#define BCAP 4096       // max edges per bucket (mean 2046, +45 sigma) -> 16KB LDS

typedef __attribute__((ext_vector_type(8))) short bf16x8;
typedef __attribute__((ext_vector_type(4))) float f32x4;

__device__ inline ushort f2bf(float f) {
    uint u = __float_as_uint(f);
    u += 0x7fffu + ((u >> 16) & 1u);   // RNE
    return (ushort)(u >> 16);
}
__device__ inline uint pack2(float lo, float hi) {
    return (uint)f2bf(lo) | ((uint)f2bf(hi) << 16);
}

// out[n][j] = relu(b[j] + sum_k in[n][k] * W[j][k])  (+ xres[n][j] if RESID)
// MFMA 16x16x32 bf16; one wave per 16-row tile (in-place safe for RESID).
// A and B use the same assumed k-bijection (dot invariant); C layout is the
// m89-verified col=lane&15, row=(lane>>4)*4+reg.  [unchanged since round 3]
template<bool RESID, bool BF16OUT>
__global__ __launch_bounds__(256, 2)
void linear_mfma_kernel(const float* in, const float* __restrict__ W,
                        const float* __restrict__ b, const float* __restrict__ xres,
                        void* outv, int n_tiles)
{
    __shared__ uint4 Wl[128 * 16];   // 32 KB, 16B-chunk XOR swizzle

    const int t = threadIdx.x;
    for (int q = t; q < 2048; q += 256) {
        const int j = q >> 4, c = q & 15;
        const float4 lo = ((const float4*)(W + j * 128 + c * 8))[0];
        const float4 hi = ((const float4*)(W + j * 128 + c * 8))[1];
        uint4 pk;
        pk.x = pack2(lo.x, lo.y); pk.y = pack2(lo.z, lo.w);
        pk.z = pack2(hi.x, hi.y); pk.w = pack2(hi.z, hi.w);
        Wl[j * 16 + (c ^ (j & 15))] = pk;
    }
    __syncthreads();

    const int lane = t & 63;
    const int lo4 = lane & 15;
    const int g   = lane >> 4;

    float bias[8];
    #pragma unroll
    for (int ct = 0; ct < 8; ++ct) bias[ct] = b[ct * 16 + lo4];

    const int wid = (blockIdx.x * 256 + t) >> 6;
    const int nw  = (gridDim.x * 256) >> 6;

    for (int tile = wid; tile < n_tiles; tile += nw) {
        const int arow = tile * 16 + lo4;
        const float4* ap = (const float4*)(in + (size_t)arow * DIM + g * 32);
        float4 v[8];
        #pragma unroll
        for (int i = 0; i < 8; ++i) v[i] = ap[i];

        bf16x8 afrag[4];
        #pragma unroll
        for (int ks = 0; ks < 4; ++ks) {
            union { bf16x8 v8; uint u[4]; } a;
            a.u[0] = pack2(v[2*ks].x,   v[2*ks].y);
            a.u[1] = pack2(v[2*ks].z,   v[2*ks].w);
            a.u[2] = pack2(v[2*ks+1].x, v[2*ks+1].y);
            a.u[3] = pack2(v[2*ks+1].z, v[2*ks+1].w);
            afrag[ks] = a.v8;
        }

        f32x4 acc[8];
        #pragma unroll
        for (int ct = 0; ct < 8; ++ct)
            acc[ct] = (f32x4){bias[ct], bias[ct], bias[ct], bias[ct]};

        #pragma unroll
        for (int ks = 0; ks < 4; ++ks) {
            #pragma unroll
            for (int ct = 0; ct < 8; ++ct) {
                const int jrow = ct * 16 + lo4;
                const bf16x8 bfrag = *((const bf16x8*)&Wl[jrow * 16 + ((g * 4 + ks) ^ lo4)]);
                acc[ct] = __builtin_amdgcn_mfma_f32_16x16x32_bf16(afrag[ks], bfrag, acc[ct], 0, 0, 0);
            }
        }

        #pragma unroll
        for (int ct = 0; ct < 8; ++ct) {
            #pragma unroll
            for (int r = 0; r < 4; ++r) {
                const int orow = tile * 16 + g * 4 + r;
                const int ocol = ct * 16 + lo4;
                float val = fmaxf(acc[ct][r], 0.f);
                if constexpr (RESID) val += xres[(size_t)orow * DIM + ocol];
                if constexpr (BF16OUT)
                    ((ushort*)outv)[(size_t)orow * DIM + ocol] = f2bf(val);
                else
                    ((float*)outv)[(size_t)orow * DIM + ocol] = val;
            }
        }
    }
}

// Pass 1: per-bucket histogram (LDS int hist, one global atomic per (block,bucket))
__global__ __launch_bounds__(256)
void bucket_count_kernel(const int* __restrict__ ei, int* __restrict__ ghist,
                         int n_edges, int nb)
{
    __shared__ int h[NBMAX];
    const int t = threadIdx.x;
    for (int i = t; i < nb; i += 256) h[i] = 0;
    __syncthreads();
    const int stride = gridDim.x * 256;
    for (int e = blockIdx.x * 256 + t; e < n_edges; e += stride)
        atomicAdd(&h[ei[n_edges + e] >> 7], 1);
    __syncthreads();
    for (int i = t; i < nb; i += 256)
        if (h[i]) atomicAdd(&ghist[i], h[i]);
}

// Pass 2: exclusive scan of nb (<1024) bucket counts -> goff, gcur
__global__ __launch_bounds__(1024)
void bucket_scan_kernel(const int* __restrict__ ghist, int* __restrict__ goff,
                        int* __restrict__ gcur, int nb, int total)
{
    __shared__ int s[1024];
    const int t = threadIdx.x;
    const int v = t < nb ? ghist[t] : 0;
    s[t] = v;
    __syncthreads();
    for (int off = 1; off < 1024; off <<= 1) {
        const int add = t >= off ? s[t - off] : 0;
        __syncthreads();
        s[t] += add;
        __syncthreads();
    }
    const int excl = s[t] - v;
    if (t < nb) { goff[t] = excl; gcur[t] = excl; }
    if (t == 0) goff[nb] = total;
}

// Pass 3: scatter packed edges (src<<7 | dst_local) into bucket regions.
// Per-block LDS hist reserves a contiguous run per (block,bucket) -> ~64B runs.
__global__ __launch_bounds__(256)
void bucket_scatter_kernel(const int* __restrict__ ei, int* __restrict__ gcur,
                           uint* __restrict__ bedges, int n_edges, int nb)
{
    __shared__ int histL[NBMAX];
    __shared__ int curL[NBMAX];
    const int t = threadIdx.x;
    for (int i = t; i < nb; i += 256) histL[i] = 0;
    __syncthreads();
    const int chunk = (n_edges + gridDim.x - 1) / gridDim.x;
    const int e0 = blockIdx.x * chunk;
    const int e1 = min(e0 + chunk, n_edges);
    for (int e = e0 + t; e < e1; e += 256)
        atomicAdd(&histL[ei[n_edges + e] >> 7], 1);
    __syncthreads();
    for (int i = t; i < nb; i += 256)
        curL[i] = histL[i] ? atomicAdd(&gcur[i], histL[i]) : 0;
    __syncthreads();
    for (int e = e0 + t; e < e1; e += 256) {
        const int src = ei[e];
        const int dst = ei[n_edges + e];
        const int b = dst >> 7;
        const int pos = atomicAdd(&curL[b], 1);
        bedges[pos] = ((uint)src << 7) | (uint)(dst & 127);
    }
}

// Pass 4: per-bucket gather. Sort the bucket's edges to exact-node order in
// LDS (int atomics only), then round-3-style pull: one wave per node, broadcast
// src from LDS, coalesced 256B msg reads, register accumulation, one row write.
__global__ __launch_bounds__(512)
void bucket_gather_kernel(const uint* __restrict__ msg, const int* __restrict__ goff,
                          const uint* __restrict__ bedges, float* __restrict__ agg,
                          int n_nodes)
{
    __shared__ int srcL[BCAP];       // 16 KB
    __shared__ int histL[BNODES];
    __shared__ int inclL[BNODES];    // inclusive scan
    __shared__ int cursL[BNODES];

    const int t = threadIdx.x;
    const int b = blockIdx.x;
    const int s0 = goff[b], s1 = goff[b + 1];

    if (t < BNODES) histL[t] = 0;
    __syncthreads();
    for (int i = s0 + t; i < s1; i += 512)
        atomicAdd(&histL[bedges[i] & 127u], 1);
    __syncthreads();
    if (t < BNODES) inclL[t] = histL[t];
    for (int off = 1; off < BNODES; off <<= 1) {
        int add = 0;
        __syncthreads();
        if (t < BNODES && t >= off) add = inclL[t - off];
        __syncthreads();
        if (t < BNODES) inclL[t] += add;
    }
    __syncthreads();
    if (t < BNODES) cursL[t] = inclL[t] - histL[t];   // exclusive start
    __syncthreads();
    for (int i = s0 + t; i < s1; i += 512) {
        const uint p = bedges[i];
        const int dl = (int)(p & 127u);
        const int pos = atomicAdd(&cursL[dl], 1);
        srcL[pos] = (int)(p >> 7);
    }
    __syncthreads();

    const int lane = t & 63;
    const int w = t >> 6;            // 8 waves
    for (int dl = w; dl < BNODES; dl += 8) {
        const int node = b * BNODES + dl;
        if (node >= n_nodes) break;          // wave-uniform
        const int e1 = inclL[dl];
        const int e0 = e1 - histL[dl];
        float a0 = 0.f, a1 = 0.f;
        int i = e0;
        for (; i + 4 <= e1; i += 4) {
            const int sA = srcL[i + 0], sB = srcL[i + 1];
            const int sC = srcL[i + 2], sD = srcL[i + 3];
            const uint mA = msg[(size_t)sA * 64 + lane];
            const uint mB = msg[(size_t)sB * 64 + lane];
            const uint mC = msg[(size_t)sC * 64 + lane];
            const uint mD = msg[(size_t)sD * 64 + lane];
            a0 += __uint_as_float(mA << 16) + __uint_as_float(mB << 16)
                + __uint_as_float(mC << 16) + __uint_as_float(mD << 16);
            a1 += __uint_as_float(mA & 0xffff0000u) + __uint_as_float(mB & 0xffff0000u)
                + __uint_as_float(mC & 0xffff0000u) + __uint_as_float(mD & 0xffff0000u);
        }
        for (; i < e1; ++i) {
            const uint m = msg[(size_t)srcL[i] * 64 + lane];
            a0 += __uint_as_float(m << 16);
            a1 += __uint_as_float(m & 0xffff0000u);
        }
        ((float2*)(agg + (size_t)node * DIM))[lane] = make_float2(a0, a1);
    }
}

extern "C" void kernel_launch(void* const* d_in, const int* in_sizes, int n_in,
                              void* d_out, int out_size, void* d_ws, size_t ws_size,
                              hipStream_t stream)
{
    const float* x  = (const float*)d_in[0];
    const int*   ei = (const int*)d_in[1];
    const float* Wm = (const float*)d_in[2];
    const float* bm = (const float*)d_in[3];
    const float* Wu = (const float*)d_in[4];
    const float* bu = (const float*)d_in[5];

    const int N = in_sizes[0] / DIM;   // 100000
    const int E = in_sizes[1] / 2;     // 1600000
    const int nb = (N + BNODES - 1) / BNODES;   // 782

    // workspace: msg 25.6MB | hist/offs/cursors ~12KB | bedges 6.4MB (~32MB used)
    char* ws = (char*)d_ws;
    ushort* msg = (ushort*)ws;
    size_t o = (size_t)N * DIM * sizeof(ushort);
    int* ghist = (int*)(ws + o); o += (size_t)NBMAX * 4;
    int* goff  = (int*)(ws + o); o += (size_t)(NBMAX + 1) * 4;
    int* gcur  = (int*)(ws + o); o += (size_t)NBMAX * 4;
    o = (o + 255) & ~(size_t)255;
    uint* bedges = (uint*)(ws + o);

    float* out = (float*)d_out;
    float* agg = out;                  // agg lives in d_out; update runs in-place

    const int n_tiles = N / 16;

    // 1) messages (bf16) = relu(x @ Wm^T + bm) -> ws
    linear_mfma_kernel<false, true><<<512, 256, 0, stream>>>(x, Wm, bm, nullptr, msg, n_tiles);

    // 2) bucket partition (128 nodes/bucket)
    hipMemsetAsync(ghist, 0, (size_t)nb * 4, stream);
    bucket_count_kernel<<<256, 256, 0, stream>>>(ei, ghist, E, nb);
    bucket_scan_kernel<<<1, 1024, 0, stream>>>(ghist, goff, gcur, nb, E);
    bucket_scatter_kernel<<<128, 256, 0, stream>>>(ei, gcur, bedges, E, nb);

    // 3) per-bucket LDS sort + pull gather -> d_out (full coverage, no memset)
    bucket_gather_kernel<<<nb, 512, 0, stream>>>((const uint*)msg, goff, bedges, agg, N);

    // 4) out = relu(agg @ Wu^T + bu) + x   (in-place on d_out)
    linear_mfma_kernel<true, false><<<512, 256, 0, stream>>>(agg, Wu, bu, x, out, n_tiles);
}